// Round 16
// baseline (179.686 us; speedup 1.0000x reference)
//
#include <hip/hip_runtime.h>

#define SQL  1024
#define EDIM 256
#define NHD  8
#define NKV  (NHD * 3 * EDIM)   // 6144
#define MROWS (4 * SQL)         // 4096

typedef short bf16x8 __attribute__((ext_vector_type(8)));
typedef float f32x4 __attribute__((ext_vector_type(4)));

__device__ __forceinline__ unsigned short f2bf(float f) {
  unsigned u = __float_as_uint(f);
  u += 0x7fff + ((u >> 16) & 1);   // round-to-nearest-even (finite values)
  return (unsigned short)(u >> 16);
}

// async 16B global->LDS (direct-to-shared DMA; LDS dest must be
// wave-uniform base + lane*16 — all call sites use flat (it*256+tid)*16B)
__device__ __forceinline__ void g2lds16(const void* g, void* l) {
  __builtin_amdgcn_global_load_lds(
      (const __attribute__((address_space(1))) unsigned int*)g,
      (__attribute__((address_space(3))) unsigned int*)l, 16, 0, 0);
}

__device__ __forceinline__ void storev(float* p, float v) { *p = v; }
__device__ __forceinline__ void storev(unsigned short* p, float v) { *p = f2bf(v); }

// =====================================================================
// fused fp32 -> bf16 cast for x / w_attn / w_out + fp32 zero-fill of
// out (replaces the hipMemsetAsync launch). 8 elems/thread.
// =====================================================================
__global__ __launch_bounds__(256) void cast3_bf16(
    const float* __restrict__ s0, unsigned short* __restrict__ d0, int n0,
    const float* __restrict__ s1, unsigned short* __restrict__ d1, int n1,
    const float* __restrict__ s2, unsigned short* __restrict__ d2, int n2,
    float* __restrict__ zout, int n3) {
  int i = blockIdx.x * 256 + threadIdx.x;
  const float* s; unsigned short* d;
  if (i >= n0 + n1 + n2) {            // zero-fill segment
    i -= n0 + n1 + n2;
    if (i >= n3) return;
    float4 z = {0.f, 0.f, 0.f, 0.f};
    ((float4*)zout)[2 * i] = z;
    ((float4*)zout)[2 * i + 1] = z;
    return;
  }
  if (i < n0) { s = s0; d = d0; }
  else if (i < n0 + n1) { i -= n0; s = s1; d = d1; }
  else { i -= n0 + n1; s = s2; d = d2; }
  float4 a = ((const float4*)s)[2 * i];
  float4 b = ((const float4*)s)[2 * i + 1];
  union { unsigned short u[8]; ulonglong2 v; } t;
  t.u[0] = f2bf(a.x); t.u[1] = f2bf(a.y); t.u[2] = f2bf(a.z); t.u[3] = f2bf(a.w);
  t.u[4] = f2bf(b.x); t.u[5] = f2bf(b.y); t.u[6] = f2bf(b.z); t.u[7] = f2bf(b.w);
  ((ulonglong2*)d)[i] = t.v;
}

// =====================================================================
// bf16 MFMA NT-GEMM (QKV projection), round-0 proven loop + XCD-chunked
// 1D block decode (neutral-to-positive, kept).
// =====================================================================
template <int BM, int BN, typename OutT>
__global__ __launch_bounds__(256) void gemm_mfma(
    const unsigned short* __restrict__ A, const unsigned short* __restrict__ B,
    const float* __restrict__ bias, OutT* __restrict__ C,
    int M, int N, int K) {
  constexpr int TM = BM / 32, TN = BN / 32;
  __shared__ __align__(16) unsigned short As[2][BM * 32];
  __shared__ __align__(16) unsigned short Bs[2][BN * 32];
  const int tid = threadIdx.x;
  const int wave = tid >> 6, lane = tid & 63;
  const int quad = lane >> 4, l16 = lane & 15;
  const int wm = (wave >> 1) * (BM / 2), wn = (wave & 1) * (BN / 2);
  const int chunk = gridDim.x >> 3;
  const int nb = (blockIdx.x & 7) * chunk + (blockIdx.x >> 3);
  const int nbm = M / BM;
  const int m0 = (nb % nbm) * BM, n0 = (nb / nbm) * BN;
  const int sw = (l16 >> 1) & 3;

  f32x4 acc[TM][TN];
  #pragma unroll
  for (int i = 0; i < TM; i++)
    #pragma unroll
    for (int j = 0; j < TN; j++) acc[i][j] = {0.f, 0.f, 0.f, 0.f};

  auto stage = [&](int k0, int bb) {
    #pragma unroll
    for (int it = 0; it < BM / 64; it++) {
      int flat = it * 256 + tid;
      int row = flat >> 2;
      int cg = (flat & 3) ^ ((row >> 1) & 3);
      g2lds16(A + (size_t)(m0 + row) * K + k0 + cg * 8, &As[bb][flat * 8]);
    }
    #pragma unroll
    for (int it = 0; it < BN / 64; it++) {
      int flat = it * 256 + tid;
      int row = flat >> 2;
      int cg = (flat & 3) ^ ((row >> 1) & 3);
      g2lds16(B + (size_t)(n0 + row) * K + k0 + cg * 8, &Bs[bb][flat * 8]);
    }
  };

  stage(0, 0);
  __syncthreads();
  for (int k0 = 0; k0 < K; k0 += 32) {
    const int bb = (k0 >> 5) & 1;
    if (k0 + 32 < K) stage(k0 + 32, bb ^ 1);
    bf16x8 af[TM], bf[TN];
    #pragma unroll
    for (int i = 0; i < TM; i++)
      af[i] = *(const bf16x8*)&As[bb][(wm + i * 16 + l16) * 32 + (quad ^ sw) * 8];
    #pragma unroll
    for (int j = 0; j < TN; j++)
      bf[j] = *(const bf16x8*)&Bs[bb][(wn + j * 16 + l16) * 32 + (quad ^ sw) * 8];
    #pragma unroll
    for (int i = 0; i < TM; i++)
      #pragma unroll
      for (int j = 0; j < TN; j++)
        acc[i][j] = __builtin_amdgcn_mfma_f32_16x16x32_bf16(af[i], bf[j], acc[i][j], 0, 0, 0);
    __syncthreads();  // gates buffer reuse + drains this iter's prefetch
  }

  #pragma unroll
  for (int i = 0; i < TM; i++) {
    #pragma unroll
    for (int r = 0; r < 4; r++) {
      int m = m0 + wm + i * 16 + quad * 4 + r;
      #pragma unroll
      for (int j = 0; j < TN; j++) {
        int n = n0 + wn + j * 16 + l16;
        storev(&C[(size_t)m * N + n], acc[i][j][r] + bias[n]);
      }
    }
  }
}

// =====================================================================
// Split-K bf16 MFMA NT-GEMM (output projection), BK=64 staging, BN=128.
// Split-K 4->8 (KCH=256): each block runs only 4 stage->drain
// iterations (vs 8), and 1024 blocks give 3-4 co-resident blocks/CU
// (vs 2) so barrier drains overlap across independent blocks — the two
// levers this session measured as decisive for latency-bound chains.
// Atomics double to 8.4M fp32 (rate analysis: trivial). z==0 folds
// bias; fp32 atomicAdd into pre-zeroed out.
// grid (64,2,8) = 1024 blocks; LDS 48KB -> 3 blocks/CU.
// =====================================================================
template <int BM, int BN, int KCH>
__global__ __launch_bounds__(256) void gemm_splitk(
    const unsigned short* __restrict__ A, const unsigned short* __restrict__ B,
    const float* __restrict__ bias, float* __restrict__ C,
    int M, int N, int K) {
  constexpr int TM = BM / 32, TN = BN / 32;
  __shared__ __align__(16) unsigned short As[2][BM * 64];
  __shared__ __align__(16) unsigned short Bs[2][BN * 64];
  const int tid = threadIdx.x;
  const int wave = tid >> 6, lane = tid & 63;
  const int quad = lane >> 4, l16 = lane & 15;
  const int wm = (wave >> 1) * (BM / 2), wn = (wave & 1) * (BN / 2);
  const int m0 = blockIdx.x * BM, n0 = blockIdx.y * BN;
  const int kbase = blockIdx.z * KCH;

  f32x4 acc[TM][TN];
  #pragma unroll
  for (int j = 0; j < TN; j++) {
    const float bb = (blockIdx.z == 0) ? bias[n0 + wn + j * 16 + l16] : 0.f;
    #pragma unroll
    for (int i = 0; i < TM; i++) acc[i][j] = {bb, bb, bb, bb};
  }

  auto stage = [&](int k0, int bb) {
    #pragma unroll
    for (int it = 0; it < BM / 32; it++) {   // BM x 64 chunk
      int flat = it * 256 + tid;
      int row = flat >> 3;
      int cg = (flat & 7) ^ (row & 7);
      g2lds16(A + (size_t)(m0 + row) * K + k0 + cg * 8, &As[bb][flat * 8]);
    }
    #pragma unroll
    for (int it = 0; it < BN / 32; it++) {   // BN x 64 chunk
      int flat = it * 256 + tid;
      int row = flat >> 3;
      int cg = (flat & 7) ^ (row & 7);
      g2lds16(B + (size_t)(n0 + row) * K + k0 + cg * 8, &Bs[bb][flat * 8]);
    }
  };

  stage(kbase, 0);
  __syncthreads();
  for (int kk = 0; kk < KCH; kk += 64) {
    const int bb = (kk >> 6) & 1;
    if (kk + 64 < KCH) stage(kbase + kk + 64, bb ^ 1);
    #pragma unroll
    for (int s = 0; s < 2; s++) {     // two K=32 sub-steps per staged chunk
      bf16x8 af[TM], bf[TN];
      #pragma unroll
      for (int i = 0; i < TM; i++) {
        const int row = wm + i * 16 + l16;
        af[i] = *(const bf16x8*)&As[bb][row * 64 + (((s * 4 + quad) ^ (l16 & 7)) * 8)];
      }
      #pragma unroll
      for (int j = 0; j < TN; j++) {
        const int row = wn + j * 16 + l16;
        bf[j] = *(const bf16x8*)&Bs[bb][row * 64 + (((s * 4 + quad) ^ (l16 & 7)) * 8)];
      }
      #pragma unroll
      for (int i = 0; i < TM; i++)
        #pragma unroll
        for (int j = 0; j < TN; j++)
          acc[i][j] = __builtin_amdgcn_mfma_f32_16x16x32_bf16(af[i], bf[j], acc[i][j], 0, 0, 0);
    }
    __syncthreads();
  }

  #pragma unroll
  for (int i = 0; i < TM; i++) {
    #pragma unroll
    for (int r = 0; r < 4; r++) {
      int m = m0 + wm + i * 16 + quad * 4 + r;
      #pragma unroll
      for (int j = 0; j < TN; j++) {
        int n = n0 + wn + j * 16 + l16;
        atomicAdd(&C[(size_t)m * N + n], acc[i][j][r]);
      }
    }
  }
}

// =====================================================================
// One-shot V transpose: raw-view V -> Vt[bh][d][s] bf16. (R0/R13 version)
// =====================================================================
__global__ __launch_bounds__(256) void transpose_v(
    const unsigned short* __restrict__ proj, unsigned short* __restrict__ vt) {
  __shared__ unsigned short T[64][66];
  const int tid = threadIdx.x;
  const int s0 = blockIdx.x * 64, d0 = blockIdx.y * 64, bh = blockIdx.z;
  const int b = bh >> 3, h = bh & 7;
  #pragma unroll
  for (int it = 0; it < 2; it++) {
    int c = it * 256 + tid;
    int sr = c >> 3, k8 = (c & 7) * 8;
    int s = s0 + sr;
    const unsigned short* src = proj + (size_t)(b * SQL + h * 128 + (s >> 3)) * NKV
                                + 2 * 2048 + (s & 7) * 256 + d0 + k8;
    *(ulonglong2*)&T[sr][k8] = *(const ulonglong2*)src;
  }
  __syncthreads();
  #pragma unroll
  for (int it = 0; it < 2; it++) {
    int c = it * 256 + tid;
    int dr = c >> 3, s8 = (c & 7) * 8;
    unsigned short tmp[8];
    #pragma unroll
    for (int j = 0; j < 8; j++) tmp[j] = T[s8 + j][dr];
    unsigned short* dst = vt + ((size_t)bh * EDIM + d0 + dr) * SQL + s0 + s8;
    *(ulonglong2*)dst = *(ulonglong2*)tmp;
  }
}

// =====================================================================
// bf16 MFMA flash attention — EXACT R0 version (proven 47.0-47.4us,
// local optimum across 14 tested variants; the ~1700cyc/iter
// staging+barrier fixed cost is structural, few-fat-iterations
// amortizes it best).
// =====================================================================
__global__ __launch_bounds__(256) void attn_mfma(
    const unsigned short* __restrict__ proj,
    const unsigned short* __restrict__ vt,
    unsigned short* __restrict__ oflat) {
  // shorts: Ks0 @0 (8192) | Vts0 @8192 (8192) | Ks1 @16384 | Vts1 @24576 | Ps @32768 (2560)
  __shared__ __align__(16) unsigned short lds[35328];
  unsigned short* Ps = lds + 32768;  // [64][40] padded, VGPR-written

  const int tid = threadIdx.x;
  const int wave = tid >> 6, lane = tid & 63;
  const int quad = lane >> 4, l16 = lane & 15;
  // balanced decode: slot s -> (bh = s&31, j = s>>5); round 0 heavy, 1 light
  const int slot = blockIdx.x & 255, round = blockIdx.x >> 8;
  const int bh = slot & 31;
  const int j = slot >> 5;
  const int qt = round ? j : 15 - j;
  const int b = bh >> 3, h = bh & 7;
  const int q0 = qt * 64;

  // ---- stage Q (64 x 256) through buf0 region, swizzled ----
  #pragma unroll
  for (int it = 0; it < 8; it++) {
    int c = it * 256 + tid;
    int r = c >> 5, ch = (c & 31) ^ (r & 7);
    int s = q0 + r;
    g2lds16(proj + (size_t)(b * SQL + h * 128 + (s >> 3)) * NKV + (s & 7) * 256 + ch * 8,
            lds + c * 8);
  }
  __syncthreads();
  bf16x8 aq[8];
  const int qrow = wave * 16 + l16;
  #pragma unroll
  for (int kk = 0; kk < 8; kk++)
    aq[kk] = *(const bf16x8*)&lds[qrow * 256 + ((kk * 4 + quad) ^ (qrow & 7)) * 8];
  __syncthreads();  // all waves done reading Q before buf0 overwrite

  f32x4 o[16];
  #pragma unroll
  for (int t = 0; t < 16; t++) o[t] = {0.f, 0.f, 0.f, 0.f};
  float l_r[4] = {0.f, 0.f, 0.f, 0.f};

  auto stage = [&](int kt, int bb) {
    unsigned short* KsB = lds + bb * 16384;
    unsigned short* VtB = KsB + 8192;
    #pragma unroll
    for (int it = 0; it < 4; it++) {   // K tile 32 x 256
      int c = it * 256 + tid;
      int r = c >> 5, ch = (c & 31) ^ (r & 7);
      int s = kt * 32 + r;
      g2lds16(proj + (size_t)(b * SQL + h * 128 + (s >> 3)) * NKV + 2048 + (s & 7) * 256 + ch * 8,
              KsB + c * 8);
    }
    #pragma unroll
    for (int it = 0; it < 4; it++) {   // Vt tile 256 x 32
      int c = it * 256 + tid;
      int d = c >> 2, ch = (c & 3) ^ (d & 3);
      g2lds16(vt + ((size_t)bh * EDIM + d) * SQL + kt * 32 + ch * 8, VtB + c * 8);
    }
  };

  const int nkt = 2 * qt + 2;
  stage(0, 0);
  __syncthreads();  // drain kt=0 (exposed once)

  for (int kt = 0; kt < nkt; kt++) {
    const int bb = kt & 1;
    if (kt + 1 < nkt) stage(kt + 1, bb ^ 1);  // prefetch into other buffer
    const unsigned short* KsB = lds + bb * 16384;
    const unsigned short* VtB = KsB + 8192;

    // ---- S = Q K^T (two 16-col tiles) ----
    f32x4 s0 = {0.f, 0.f, 0.f, 0.f}, s1 = {0.f, 0.f, 0.f, 0.f};
    #pragma unroll
    for (int kk = 0; kk < 8; kk++) {
      int ch = (kk * 4 + quad) ^ (l16 & 7);
      bf16x8 b0 = *(const bf16x8*)&KsB[l16 * 256 + ch * 8];
      bf16x8 b1 = *(const bf16x8*)&KsB[(16 + l16) * 256 + ch * 8];
      s0 = __builtin_amdgcn_mfma_f32_16x16x32_bf16(aq[kk], b0, s0, 0, 0, 0);
      s1 = __builtin_amdgcn_mfma_f32_16x16x32_bf16(aq[kk], b1, s1, 0, 0, 0);
    }

    // ---- shift-free softmax: p = exp(s/16), lane-local l partials ----
    const int kg0 = kt * 32 + l16, kg1 = kg0 + 16;
    #pragma unroll
    for (int r = 0; r < 4; r++) {
      int qg = q0 + wave * 16 + quad * 4 + r;
      float p0 = (kg0 <= qg) ? __expf(s0[r] * 0.0625f) : 0.f;
      float p1 = (kg1 <= qg) ? __expf(s1[r] * 0.0625f) : 0.f;
      l_r[r] += p0 + p1;
      Ps[(wave * 16 + quad * 4 + r) * 40 + l16]      = f2bf(p0);
      Ps[(wave * 16 + quad * 4 + r) * 40 + 16 + l16] = f2bf(p1);
    }

    // ---- PV: P C->A layout via same-wave LDS round-trip ----
    bf16x8 ap = *(const bf16x8*)&Ps[(wave * 16 + l16) * 40 + quad * 8];
    #pragma unroll
    for (int t = 0; t < 16; t++) {
      bf16x8 bv = *(const bf16x8*)&VtB[(t * 16 + l16) * 32 + (quad ^ (l16 & 3)) * 8];
      o[t] = __builtin_amdgcn_mfma_f32_16x16x32_bf16(ap, bv, o[t], 0, 0, 0);
    }
    __syncthreads();  // buffer reuse gate + drains this iter's prefetch
  }

  // ---- epilogue: reduce l across the 16-lane group, O /= l, scatter ----
  #pragma unroll
  for (int r = 0; r < 4; r++) {
    float l = l_r[r];
    #pragma unroll
    for (int off = 1; off < 16; off <<= 1) l += __shfl_xor(l, off);
    float inv = 1.0f / l;
    int s = q0 + wave * 16 + quad * 4 + r;
    unsigned short* dst = oflat + (size_t)(b * SQL + h * 128 + (s >> 3)) * 2048 + (s & 7) * 256;
    #pragma unroll
    for (int t = 0; t < 16; t++)
      dst[t * 16 + l16] = f2bf(o[t][r] * inv);
  }
}

extern "C" void kernel_launch(void* const* d_in, const int* in_sizes, int n_in,
                              void* d_out, int out_size, void* d_ws, size_t ws_size,
                              hipStream_t stream) {
  const float* x      = (const float*)d_in[0];
  const float* w_attn = (const float*)d_in[1];
  const float* b_attn = (const float*)d_in[2];
  const float* w_out  = (const float*)d_in[3];
  const float* b_out  = (const float*)d_in[4];
  float* out = (float*)d_out;

  char* p = (char*)d_ws;
  unsigned short* proj = (unsigned short*)p;  p += (size_t)MROWS * NKV * 2;
  unsigned short* obf  = (unsigned short*)p;  p += (size_t)MROWS * 2048 * 2;
  unsigned short* vtb  = (unsigned short*)p;  p += (size_t)32 * EDIM * SQL * 2;
  unsigned short* xb   = (unsigned short*)p;  p += (size_t)MROWS * EDIM * 2;
  unsigned short* wb   = (unsigned short*)p;  p += (size_t)NKV * EDIM * 2;
  unsigned short* wob  = (unsigned short*)p;

  const int n0 = MROWS * EDIM / 8;        // 131072
  const int n1 = NKV * EDIM / 8;          // 196608
  const int n2 = EDIM * 2048 / 8;         // 65536
  const int n3 = MROWS * EDIM / 8;        // 131072 (fp32 zero-fill, 8 floats/thr)
  cast3_bf16<<<(n0 + n1 + n2 + n3) / 256, 256, 0, stream>>>(
      x, xb, n0, w_attn, wb, n1, w_out, wob, n2, out, n3);

  gemm_mfma<128, 128, unsigned short><<<(MROWS / 128) * (NKV / 128), 256, 0, stream>>>(
      xb, wb, b_attn, proj, MROWS, NKV, EDIM);
  transpose_v<<<dim3(SQL / 64, EDIM / 64, 32), 256, 0, stream>>>(proj, vtb);
  attn_mfma<<<512, 256, 0, stream>>>(proj, vtb, obf);
  gemm_splitk<64, 128, 256><<<dim3(MROWS / 64, EDIM / 128, 8), 256, 0, stream>>>(
      obf, wob, b_out, out, MROWS, EDIM, NHD * EDIM);
}

// Round 17
// 156.450 us; speedup vs baseline: 1.1485x; 1.1485x over previous
//
#include <hip/hip_runtime.h>

#define SQL  1024
#define EDIM 256
#define NHD  8
#define NKV  (NHD * 3 * EDIM)   // 6144
#define MROWS (4 * SQL)         // 4096

typedef short bf16x8 __attribute__((ext_vector_type(8)));
typedef float f32x4 __attribute__((ext_vector_type(4)));

__device__ __forceinline__ unsigned short f2bf(float f) {
  unsigned u = __float_as_uint(f);
  u += 0x7fff + ((u >> 16) & 1);   // round-to-nearest-even (finite values)
  return (unsigned short)(u >> 16);
}

// async 16B global->LDS (direct-to-shared DMA; LDS dest must be
// wave-uniform base + lane*16 — all call sites use flat (it*256+tid)*16B)
__device__ __forceinline__ void g2lds16(const void* g, void* l) {
  __builtin_amdgcn_global_load_lds(
      (const __attribute__((address_space(1))) unsigned int*)g,
      (__attribute__((address_space(3))) unsigned int*)l, 16, 0, 0);
}

__device__ __forceinline__ void storev(float* p, float v) { *p = v; }
__device__ __forceinline__ void storev(unsigned short* p, float v) { *p = f2bf(v); }

// =====================================================================
// fused fp32 -> bf16 cast for x / w_attn / w_out. 8 elems/thread.
// (zero-fill segment removed: reduce4 now writes every out element.)
// =====================================================================
__global__ __launch_bounds__(256) void cast3_bf16(
    const float* __restrict__ s0, unsigned short* __restrict__ d0, int n0,
    const float* __restrict__ s1, unsigned short* __restrict__ d1, int n1,
    const float* __restrict__ s2, unsigned short* __restrict__ d2, int n2) {
  int i = blockIdx.x * 256 + threadIdx.x;
  const float* s; unsigned short* d;
  if (i < n0) { s = s0; d = d0; }
  else if (i < n0 + n1) { i -= n0; s = s1; d = d1; }
  else { i -= n0 + n1; if (i >= n2) return; s = s2; d = d2; }
  float4 a = ((const float4*)s)[2 * i];
  float4 b = ((const float4*)s)[2 * i + 1];
  union { unsigned short u[8]; ulonglong2 v; } t;
  t.u[0] = f2bf(a.x); t.u[1] = f2bf(a.y); t.u[2] = f2bf(a.z); t.u[3] = f2bf(a.w);
  t.u[4] = f2bf(b.x); t.u[5] = f2bf(b.y); t.u[6] = f2bf(b.z); t.u[7] = f2bf(b.w);
  ((ulonglong2*)d)[i] = t.v;
}

// =====================================================================
// bf16 MFMA NT-GEMM (QKV projection), round-0 proven loop + XCD-chunked
// 1D block decode (neutral-to-positive, kept).
// =====================================================================
template <int BM, int BN, typename OutT>
__global__ __launch_bounds__(256) void gemm_mfma(
    const unsigned short* __restrict__ A, const unsigned short* __restrict__ B,
    const float* __restrict__ bias, OutT* __restrict__ C,
    int M, int N, int K) {
  constexpr int TM = BM / 32, TN = BN / 32;
  __shared__ __align__(16) unsigned short As[2][BM * 32];
  __shared__ __align__(16) unsigned short Bs[2][BN * 32];
  const int tid = threadIdx.x;
  const int wave = tid >> 6, lane = tid & 63;
  const int quad = lane >> 4, l16 = lane & 15;
  const int wm = (wave >> 1) * (BM / 2), wn = (wave & 1) * (BN / 2);
  const int chunk = gridDim.x >> 3;
  const int nb = (blockIdx.x & 7) * chunk + (blockIdx.x >> 3);
  const int nbm = M / BM;
  const int m0 = (nb % nbm) * BM, n0 = (nb / nbm) * BN;
  const int sw = (l16 >> 1) & 3;

  f32x4 acc[TM][TN];
  #pragma unroll
  for (int i = 0; i < TM; i++)
    #pragma unroll
    for (int j = 0; j < TN; j++) acc[i][j] = {0.f, 0.f, 0.f, 0.f};

  auto stage = [&](int k0, int bb) {
    #pragma unroll
    for (int it = 0; it < BM / 64; it++) {
      int flat = it * 256 + tid;
      int row = flat >> 2;
      int cg = (flat & 3) ^ ((row >> 1) & 3);
      g2lds16(A + (size_t)(m0 + row) * K + k0 + cg * 8, &As[bb][flat * 8]);
    }
    #pragma unroll
    for (int it = 0; it < BN / 64; it++) {
      int flat = it * 256 + tid;
      int row = flat >> 2;
      int cg = (flat & 3) ^ ((row >> 1) & 3);
      g2lds16(B + (size_t)(n0 + row) * K + k0 + cg * 8, &Bs[bb][flat * 8]);
    }
  };

  stage(0, 0);
  __syncthreads();
  for (int k0 = 0; k0 < K; k0 += 32) {
    const int bb = (k0 >> 5) & 1;
    if (k0 + 32 < K) stage(k0 + 32, bb ^ 1);
    bf16x8 af[TM], bf[TN];
    #pragma unroll
    for (int i = 0; i < TM; i++)
      af[i] = *(const bf16x8*)&As[bb][(wm + i * 16 + l16) * 32 + (quad ^ sw) * 8];
    #pragma unroll
    for (int j = 0; j < TN; j++)
      bf[j] = *(const bf16x8*)&Bs[bb][(wn + j * 16 + l16) * 32 + (quad ^ sw) * 8];
    #pragma unroll
    for (int i = 0; i < TM; i++)
      #pragma unroll
      for (int j = 0; j < TN; j++)
        acc[i][j] = __builtin_amdgcn_mfma_f32_16x16x32_bf16(af[i], bf[j], acc[i][j], 0, 0, 0);
    __syncthreads();  // gates buffer reuse + drains this iter's prefetch
  }

  #pragma unroll
  for (int i = 0; i < TM; i++) {
    #pragma unroll
    for (int r = 0; r < 4; r++) {
      int m = m0 + wm + i * 16 + quad * 4 + r;
      #pragma unroll
      for (int j = 0; j < TN; j++) {
        int n = n0 + wn + j * 16 + l16;
        storev(&C[(size_t)m * N + n], acc[i][j][r] + bias[n]);
      }
    }
  }
}

// =====================================================================
// Split-K bf16 MFMA NT-GEMM (output projection), BK=64, BN=128,
// split-K=4 — the R15-proven shape — with ATOMICS REPLACED by plain
// coalesced fp32 stores into a per-partition partial buffer.
// R16's isolation experiment (KCH 512->256: identical A/B traffic,
// +4.2M atomics, +14.2us) pinned fp32 L2 atomicAdd at ~3.4ns marginal
// -> R15's 4.2M atomics were ~12-14us of gemm2's ~23us. Plain stores
// cost ~3us of BW instead; reduce4 sums partials + bias into out.
// part aliases the dead proj region (stream-ordered after attn).
// =====================================================================
template <int BM, int BN, int KCH>
__global__ __launch_bounds__(256) void gemm_splitk(
    const unsigned short* __restrict__ A, const unsigned short* __restrict__ B,
    float* __restrict__ part, int M, int N, int K) {
  constexpr int TM = BM / 32, TN = BN / 32;
  __shared__ __align__(16) unsigned short As[2][BM * 64];
  __shared__ __align__(16) unsigned short Bs[2][BN * 64];
  const int tid = threadIdx.x;
  const int wave = tid >> 6, lane = tid & 63;
  const int quad = lane >> 4, l16 = lane & 15;
  const int wm = (wave >> 1) * (BM / 2), wn = (wave & 1) * (BN / 2);
  const int m0 = blockIdx.x * BM, n0 = blockIdx.y * BN;
  const int kbase = blockIdx.z * KCH;
  float* myp = part + (size_t)blockIdx.z * M * N;

  f32x4 acc[TM][TN];
  #pragma unroll
  for (int i = 0; i < TM; i++)
    #pragma unroll
    for (int j = 0; j < TN; j++) acc[i][j] = {0.f, 0.f, 0.f, 0.f};

  auto stage = [&](int k0, int bb) {
    #pragma unroll
    for (int it = 0; it < BM / 32; it++) {   // BM x 64 chunk
      int flat = it * 256 + tid;
      int row = flat >> 3;
      int cg = (flat & 7) ^ (row & 7);
      g2lds16(A + (size_t)(m0 + row) * K + k0 + cg * 8, &As[bb][flat * 8]);
    }
    #pragma unroll
    for (int it = 0; it < BN / 32; it++) {   // BN x 64 chunk
      int flat = it * 256 + tid;
      int row = flat >> 3;
      int cg = (flat & 7) ^ (row & 7);
      g2lds16(B + (size_t)(n0 + row) * K + k0 + cg * 8, &Bs[bb][flat * 8]);
    }
  };

  stage(kbase, 0);
  __syncthreads();
  for (int kk = 0; kk < KCH; kk += 64) {
    const int bb = (kk >> 6) & 1;
    if (kk + 64 < KCH) stage(kbase + kk + 64, bb ^ 1);
    #pragma unroll
    for (int s = 0; s < 2; s++) {     // two K=32 sub-steps per staged chunk
      bf16x8 af[TM], bf[TN];
      #pragma unroll
      for (int i = 0; i < TM; i++) {
        const int row = wm + i * 16 + l16;
        af[i] = *(const bf16x8*)&As[bb][row * 64 + (((s * 4 + quad) ^ (l16 & 7)) * 8)];
      }
      #pragma unroll
      for (int j = 0; j < TN; j++) {
        const int row = wn + j * 16 + l16;
        bf[j] = *(const bf16x8*)&Bs[bb][row * 64 + (((s * 4 + quad) ^ (l16 & 7)) * 8)];
      }
      #pragma unroll
      for (int i = 0; i < TM; i++)
        #pragma unroll
        for (int j = 0; j < TN; j++)
          acc[i][j] = __builtin_amdgcn_mfma_f32_16x16x32_bf16(af[i], bf[j], acc[i][j], 0, 0, 0);
    }
    __syncthreads();
  }

  #pragma unroll
  for (int i = 0; i < TM; i++) {
    #pragma unroll
    for (int r = 0; r < 4; r++) {
      int m = m0 + wm + i * 16 + quad * 4 + r;
      #pragma unroll
      for (int j = 0; j < TN; j++) {
        int n = n0 + wn + j * 16 + l16;
        myp[(size_t)m * N + n] = acc[i][j][r];
      }
    }
  }
}

// =====================================================================
// reduce4: out = sum_z part[z] + bias. 1 float4/thread, fully
// coalesced; ~20MB traffic. Each out element written exactly once.
// =====================================================================
__global__ __launch_bounds__(256) void reduce4(
    const float* __restrict__ part, const float* __restrict__ bias,
    float* __restrict__ out) {
  const int i = blockIdx.x * 256 + threadIdx.x;        // float4 index
  constexpr int N4 = EDIM / 4;                          // 64 float4 / row
  float4 a = ((const float4*)bias)[i & (N4 - 1)];
  const float4* p = (const float4*)part;
  #pragma unroll
  for (int z = 0; z < 4; z++) {
    float4 v = p[(size_t)z * (MROWS * EDIM / 4) + i];
    a.x += v.x; a.y += v.y; a.z += v.z; a.w += v.w;
  }
  ((float4*)out)[i] = a;
}

// =====================================================================
// One-shot V transpose: raw-view V -> Vt[bh][d][s] bf16. (R0/R13 version)
// =====================================================================
__global__ __launch_bounds__(256) void transpose_v(
    const unsigned short* __restrict__ proj, unsigned short* __restrict__ vt) {
  __shared__ unsigned short T[64][66];
  const int tid = threadIdx.x;
  const int s0 = blockIdx.x * 64, d0 = blockIdx.y * 64, bh = blockIdx.z;
  const int b = bh >> 3, h = bh & 7;
  #pragma unroll
  for (int it = 0; it < 2; it++) {
    int c = it * 256 + tid;
    int sr = c >> 3, k8 = (c & 7) * 8;
    int s = s0 + sr;
    const unsigned short* src = proj + (size_t)(b * SQL + h * 128 + (s >> 3)) * NKV
                                + 2 * 2048 + (s & 7) * 256 + d0 + k8;
    *(ulonglong2*)&T[sr][k8] = *(const ulonglong2*)src;
  }
  __syncthreads();
  #pragma unroll
  for (int it = 0; it < 2; it++) {
    int c = it * 256 + tid;
    int dr = c >> 3, s8 = (c & 7) * 8;
    unsigned short tmp[8];
    #pragma unroll
    for (int j = 0; j < 8; j++) tmp[j] = T[s8 + j][dr];
    unsigned short* dst = vt + ((size_t)bh * EDIM + d0 + dr) * SQL + s0 + s8;
    *(ulonglong2*)dst = *(ulonglong2*)tmp;
  }
}

// =====================================================================
// bf16 MFMA flash attention — EXACT R0 version (proven 47.0-47.4us,
// local optimum across 14 tested variants; the ~1700cyc/iter
// staging+barrier fixed cost is structural, few-fat-iterations
// amortizes it best).
// =====================================================================
__global__ __launch_bounds__(256) void attn_mfma(
    const unsigned short* __restrict__ proj,
    const unsigned short* __restrict__ vt,
    unsigned short* __restrict__ oflat) {
  // shorts: Ks0 @0 (8192) | Vts0 @8192 (8192) | Ks1 @16384 | Vts1 @24576 | Ps @32768 (2560)
  __shared__ __align__(16) unsigned short lds[35328];
  unsigned short* Ps = lds + 32768;  // [64][40] padded, VGPR-written

  const int tid = threadIdx.x;
  const int wave = tid >> 6, lane = tid & 63;
  const int quad = lane >> 4, l16 = lane & 15;
  // balanced decode: slot s -> (bh = s&31, j = s>>5); round 0 heavy, 1 light
  const int slot = blockIdx.x & 255, round = blockIdx.x >> 8;
  const int bh = slot & 31;
  const int j = slot >> 5;
  const int qt = round ? j : 15 - j;
  const int b = bh >> 3, h = bh & 7;
  const int q0 = qt * 64;

  // ---- stage Q (64 x 256) through buf0 region, swizzled ----
  #pragma unroll
  for (int it = 0; it < 8; it++) {
    int c = it * 256 + tid;
    int r = c >> 5, ch = (c & 31) ^ (r & 7);
    int s = q0 + r;
    g2lds16(proj + (size_t)(b * SQL + h * 128 + (s >> 3)) * NKV + (s & 7) * 256 + ch * 8,
            lds + c * 8);
  }
  __syncthreads();
  bf16x8 aq[8];
  const int qrow = wave * 16 + l16;
  #pragma unroll
  for (int kk = 0; kk < 8; kk++)
    aq[kk] = *(const bf16x8*)&lds[qrow * 256 + ((kk * 4 + quad) ^ (qrow & 7)) * 8];
  __syncthreads();  // all waves done reading Q before buf0 overwrite

  f32x4 o[16];
  #pragma unroll
  for (int t = 0; t < 16; t++) o[t] = {0.f, 0.f, 0.f, 0.f};
  float l_r[4] = {0.f, 0.f, 0.f, 0.f};

  auto stage = [&](int kt, int bb) {
    unsigned short* KsB = lds + bb * 16384;
    unsigned short* VtB = KsB + 8192;
    #pragma unroll
    for (int it = 0; it < 4; it++) {   // K tile 32 x 256
      int c = it * 256 + tid;
      int r = c >> 5, ch = (c & 31) ^ (r & 7);
      int s = kt * 32 + r;
      g2lds16(proj + (size_t)(b * SQL + h * 128 + (s >> 3)) * NKV + 2048 + (s & 7) * 256 + ch * 8,
              KsB + c * 8);
    }
    #pragma unroll
    for (int it = 0; it < 4; it++) {   // Vt tile 256 x 32
      int c = it * 256 + tid;
      int d = c >> 2, ch = (c & 3) ^ (d & 3);
      g2lds16(vt + ((size_t)bh * EDIM + d) * SQL + kt * 32 + ch * 8, VtB + c * 8);
    }
  };

  const int nkt = 2 * qt + 2;
  stage(0, 0);
  __syncthreads();  // drain kt=0 (exposed once)

  for (int kt = 0; kt < nkt; kt++) {
    const int bb = kt & 1;
    if (kt + 1 < nkt) stage(kt + 1, bb ^ 1);  // prefetch into other buffer
    const unsigned short* KsB = lds + bb * 16384;
    const unsigned short* VtB = KsB + 8192;

    // ---- S = Q K^T (two 16-col tiles) ----
    f32x4 s0 = {0.f, 0.f, 0.f, 0.f}, s1 = {0.f, 0.f, 0.f, 0.f};
    #pragma unroll
    for (int kk = 0; kk < 8; kk++) {
      int ch = (kk * 4 + quad) ^ (l16 & 7);
      bf16x8 b0 = *(const bf16x8*)&KsB[l16 * 256 + ch * 8];
      bf16x8 b1 = *(const bf16x8*)&KsB[(16 + l16) * 256 + ch * 8];
      s0 = __builtin_amdgcn_mfma_f32_16x16x32_bf16(aq[kk], b0, s0, 0, 0, 0);
      s1 = __builtin_amdgcn_mfma_f32_16x16x32_bf16(aq[kk], b1, s1, 0, 0, 0);
    }

    // ---- shift-free softmax: p = exp(s/16), lane-local l partials ----
    const int kg0 = kt * 32 + l16, kg1 = kg0 + 16;
    #pragma unroll
    for (int r = 0; r < 4; r++) {
      int qg = q0 + wave * 16 + quad * 4 + r;
      float p0 = (kg0 <= qg) ? __expf(s0[r] * 0.0625f) : 0.f;
      float p1 = (kg1 <= qg) ? __expf(s1[r] * 0.0625f) : 0.f;
      l_r[r] += p0 + p1;
      Ps[(wave * 16 + quad * 4 + r) * 40 + l16]      = f2bf(p0);
      Ps[(wave * 16 + quad * 4 + r) * 40 + 16 + l16] = f2bf(p1);
    }

    // ---- PV: P C->A layout via same-wave LDS round-trip ----
    bf16x8 ap = *(const bf16x8*)&Ps[(wave * 16 + l16) * 40 + quad * 8];
    #pragma unroll
    for (int t = 0; t < 16; t++) {
      bf16x8 bv = *(const bf16x8*)&VtB[(t * 16 + l16) * 32 + (quad ^ (l16 & 3)) * 8];
      o[t] = __builtin_amdgcn_mfma_f32_16x16x32_bf16(ap, bv, o[t], 0, 0, 0);
    }
    __syncthreads();  // buffer reuse gate + drains this iter's prefetch
  }

  // ---- epilogue: reduce l across the 16-lane group, O /= l, scatter ----
  #pragma unroll
  for (int r = 0; r < 4; r++) {
    float l = l_r[r];
    #pragma unroll
    for (int off = 1; off < 16; off <<= 1) l += __shfl_xor(l, off);
    float inv = 1.0f / l;
    int s = q0 + wave * 16 + quad * 4 + r;
    unsigned short* dst = oflat + (size_t)(b * SQL + h * 128 + (s >> 3)) * 2048 + (s & 7) * 256;
    #pragma unroll
    for (int t = 0; t < 16; t++)
      dst[t * 16 + l16] = f2bf(o[t][r] * inv);
  }
}

extern "C" void kernel_launch(void* const* d_in, const int* in_sizes, int n_in,
                              void* d_out, int out_size, void* d_ws, size_t ws_size,
                              hipStream_t stream) {
  const float* x      = (const float*)d_in[0];
  const float* w_attn = (const float*)d_in[1];
  const float* b_attn = (const float*)d_in[2];
  const float* w_out  = (const float*)d_in[3];
  const float* b_out  = (const float*)d_in[4];
  float* out = (float*)d_out;

  char* p = (char*)d_ws;
  unsigned short* proj = (unsigned short*)p;  p += (size_t)MROWS * NKV * 2;
  unsigned short* obf  = (unsigned short*)p;  p += (size_t)MROWS * 2048 * 2;
  unsigned short* vtb  = (unsigned short*)p;  p += (size_t)32 * EDIM * SQL * 2;
  unsigned short* xb   = (unsigned short*)p;  p += (size_t)MROWS * EDIM * 2;
  unsigned short* wb   = (unsigned short*)p;  p += (size_t)NKV * EDIM * 2;
  unsigned short* wob  = (unsigned short*)p;
  // split-K partial buffer: aliases proj (50MB >= 16.8MB), which is
  // dead once attn_mfma has completed (stream-ordered before gemm2).
  float* part = (float*)proj;

  const int n0 = MROWS * EDIM / 8;        // 131072
  const int n1 = NKV * EDIM / 8;          // 196608
  const int n2 = EDIM * 2048 / 8;         // 65536
  cast3_bf16<<<(n0 + n1 + n2) / 256, 256, 0, stream>>>(
      x, xb, n0, w_attn, wb, n1, w_out, wob, n2);

  gemm_mfma<128, 128, unsigned short><<<(MROWS / 128) * (NKV / 128), 256, 0, stream>>>(
      xb, wb, b_attn, proj, MROWS, NKV, EDIM);
  transpose_v<<<dim3(SQL / 64, EDIM / 64, 32), 256, 0, stream>>>(proj, vtb);
  attn_mfma<<<512, 256, 0, stream>>>(proj, vtb, obf);
  gemm_splitk<64, 128, 512><<<dim3(MROWS / 64, EDIM / 128, 4), 256, 0, stream>>>(
      obf, wob, part, MROWS, EDIM, NHD * EDIM);
  reduce4<<<MROWS * EDIM / 4 / 256, 256, 0, stream>>>(part, b_out, out);
}